// Round 12
// baseline (300.634 us; speedup 1.0000x reference)
//
#include <hip/hip_runtime.h>

// out[b,c,y,x] = sum_{kdy,kdx in [0,9)} corr[b, kdy*9+kdx, y+4-kdy, x+4-kdx] * feat[b,c, y+4-kdy, x+4-kdx]
// Multi-y MFMA formulation. Block = (b, 64-ch group, 8 consecutive y), wave w owns y = y0+w.
// Iterate source rows sy = y0-4 .. y0+11 (16 steps). Per step:
//   A[c][sxp]     = feat[b, c0+c, sy, sxp-4]            (bf16, staged ONCE per row)
//   M_w[x][o]     = corr[b, kdy*9+kdx, sy, sxp-4],  kdy = w+8-s, kdx = x+8-sxp, o = sxp-kb(x)
//   (compact banded storage: per 16-wide x-tile t, K-window base kb = t<5 ? 16t : 72)
//   wave w (active iff kdy in [0,9)):  acc[ct][t] += mfma16x16x32(A-tile, M_w-tile)

#define RR 4
#define DD 9
#define D2 81
#define Bn 16
#define Cn 256
#define Hn 96
#define Wn 96
#define HWn (Hn*Wn)

#define NTH 512
#define NCB 64            // channels per block
#define NCG (Cn/NCB)      // 4
#define TY  8             // y rows per block
#define NYT (Hn/TY)       // 12
#define NST (TY+2*RR)     // 16 sy steps
#define KW  104           // A row width (sxpad 0..103) bf16; 208 B stride (16-mult, bank-clean)
#define MW  36            // M compact window width; 72 B stride (8-aligned b64 reads, bank-clean)

typedef __attribute__((ext_vector_type(8))) short bf16x8;
typedef __attribute__((ext_vector_type(4))) float f32x4;

__device__ __forceinline__ ushort f2bf(float f) {  // RNE fp32->bf16
    uint u = __float_as_uint(f);
    return (ushort)((u + 0x7FFFu + ((u >> 16) & 1u)) >> 16);
}

__global__ __launch_bounds__(NTH, 2)
void corrT12_kernel(const float* __restrict__ corr,
                    const float* __restrict__ feat,
                    float* __restrict__ out)
{
    __shared__ ushort A_sh[2][NCB][KW];        // 26624 B : feat row, bf16, dbuf
    __shared__ ushort M_sh[2][TY][Wn][MW];     // 110592 B: per-wave banded weights, dbuf

    // XCD-chunked dispatch (grid 768 = 8*96): same-b/cg y-tiles stay on one XCD
    int bid = blockIdx.x;
    int L   = (bid & 7) * 96 + (bid >> 3);
    int yt  = L % NYT;
    int t2  = L / NYT;
    int cg  = t2 & (NCG - 1);
    int b   = t2 >> 2;
    const int y0 = yt * TY;
    const int c0 = cg * NCB;

    const int tid  = threadIdx.x;
    const int lane = tid & 63;
    const int wid  = tid >> 6;            // wave w -> y0+w
    const int mrow = lane & 15;
    const int kq   = lane >> 4;           // 0..3
    const int kgrp = kq << 3;             // K sub-base 0,8,16,24

    // zero once: A pads (cols 0-3,100-103) and M out-of-band stay 0 forever
    for (int i = tid; i < (int)(sizeof(A_sh) / 4); i += NTH) ((uint*)A_sh)[i] = 0u;
    for (int i = tid; i < (int)(sizeof(M_sh) / 4); i += NTH) ((uint*)M_sh)[i] = 0u;
    __syncthreads();

    // A staging: wave wid stages channel rows [8*wid, 8*wid+8), 12 floats per lane
    const int ar  = (wid << 3) + (lane >> 3);
    const int seg = lane & 7;
    const float* fsrc = feat + (((size_t)b * Cn + c0 + ar) * Hn) * Wn + seg * 12;

#define STAGE(sv, bv) do {                                                              \
        const int sy_ = y0 - RR + (sv);                                                 \
        if (sy_ >= 0 && sy_ < Hn) {                                                     \
            const float* sp_ = fsrc + (size_t)sy_ * Wn;                                 \
            float4 v0 = *reinterpret_cast<const float4*>(sp_);                          \
            float4 v1 = *reinterpret_cast<const float4*>(sp_ + 4);                      \
            float4 v2 = *reinterpret_cast<const float4*>(sp_ + 8);                      \
            uint p0 = (uint)f2bf(v0.x) | ((uint)f2bf(v0.y) << 16);                      \
            uint p1 = (uint)f2bf(v0.z) | ((uint)f2bf(v0.w) << 16);                      \
            uint p2 = (uint)f2bf(v1.x) | ((uint)f2bf(v1.y) << 16);                      \
            uint p3 = (uint)f2bf(v1.z) | ((uint)f2bf(v1.w) << 16);                      \
            uint p4 = (uint)f2bf(v2.x) | ((uint)f2bf(v2.y) << 16);                      \
            uint p5 = (uint)f2bf(v2.z) | ((uint)f2bf(v2.w) << 16);                      \
            uint* ad_ = reinterpret_cast<uint*>(&A_sh[bv][ar][4 + seg * 12]);           \
            ad_[0] = p0; ad_[1] = p1; ad_[2] = p2;                                      \
            ad_[3] = p3; ad_[4] = p4; ad_[5] = p5;                                      \
            const int kdy_ = wid + (DD - 1) - (sv);                                     \
            if (kdy_ >= 0 && kdy_ < DD) {   /* wave builds its own M slice */           \
                const float* cb_ = corr + (((size_t)b * D2 + kdy_ * DD) * Hn + sy_) * Wn;\
                _Pragma("unroll")                                                       \
                for (int e = lane; e < DD * Wn; e += 64) {                              \
                    int kdx_ = e / Wn;                                                  \
                    int x_   = e - kdx_ * Wn;                                           \
                    int sxp_ = x_ + 2 * RR - kdx_;                                      \
                    int kbx_ = (x_ >= 80) ? 72 : (x_ & ~15);                            \
                    int sxc_ = min(max(sxp_ - RR, 0), Wn - 1);                          \
                    M_sh[bv][wid][x_][sxp_ - kbx_] = f2bf(cb_[(size_t)kdx_ * HWn + sxc_]);\
                }                                                                       \
            }                                                                           \
        }                                                                               \
    } while (0)

    f32x4 acc[4][6];
    #pragma unroll
    for (int ct = 0; ct < 4; ++ct)
        #pragma unroll
        for (int t = 0; t < 6; ++t)
            acc[ct][t] = (f32x4){0.f, 0.f, 0.f, 0.f};

    STAGE(0, 0);
    __syncthreads();

    #pragma unroll 1
    for (int s = 0; s < NST; ++s) {
        const int pb = s & 1;
        if (s + 1 < NST) STAGE(s + 1, pb ^ 1);   // loads in flight under MFMA phase

        const int sy  = y0 - RR + s;
        const int kdy = wid + (DD - 1) - s;
        if (sy >= 0 && sy < Hn && kdy >= 0 && kdy < DD) {
            #pragma unroll
            for (int t = 0; t < 6; ++t) {
                const int kb = (t == 5) ? 72 : t * 16;
                const ushort* mp = &M_sh[pb][wid][t * 16 + mrow][kgrp];
                uint2 blo = *reinterpret_cast<const uint2*>(mp);
                uint2 bhi = *reinterpret_cast<const uint2*>(mp + 4);
                uint4 bw  = make_uint4(blo.x, blo.y, bhi.x, bhi.y);
                bf16x8 bfr = *reinterpret_cast<bf16x8*>(&bw);
                #pragma unroll
                for (int ct = 0; ct < 4; ++ct) {
                    bf16x8 afr = *reinterpret_cast<const bf16x8*>(&A_sh[pb][ct * 16 + mrow][kb + kgrp]);
                    acc[ct][t] = __builtin_amdgcn_mfma_f32_16x16x32_bf16(afr, bfr, acc[ct][t], 0, 0, 0);
                }
            }
        }
        __syncthreads();
    }
#undef STAGE

    // epilogue: C/D layout col=lane&15 (x), row=(lane>>4)*4+r (c)  — R11-verified
    const int csub = kq << 2;
    const int y = y0 + wid;
    #pragma unroll
    for (int ct = 0; ct < 4; ++ct)
        #pragma unroll
        for (int t = 0; t < 6; ++t)
            #pragma unroll
            for (int r = 0; r < 4; ++r)
                out[(((size_t)b * Cn + c0 + ct * 16 + csub + r) * Hn + y) * Wn + t * 16 + mrow]
                    = acc[ct][t][r];
}

extern "C" void kernel_launch(void* const* d_in, const int* in_sizes, int n_in,
                              void* d_out, int out_size, void* d_ws, size_t ws_size,
                              hipStream_t stream)
{
    const float* corr = (const float*)d_in[0];   // [16,81,96,96]
    const float* feat = (const float*)d_in[1];   // [16,256,96,96]
    float* out = (float*)d_out;                  // [16,256,96,96]

    const int grid = Bn * NCG * NYT;             // 16*4*12 = 768
    corrT12_kernel<<<grid, NTH, 0, stream>>>(corr, feat, out);
}